// Round 2
// baseline (24.271 us; speedup 1.0000x reference)
//
#include <hip/hip_runtime.h>
#include <hip/hip_bf16.h>

#define Bc 32
#define Lc 2048
#define Hc 768
#define Dc 32
#define Cc 64

// One block (256 threads = 4 waves) per (b, d) clause.
__global__ __launch_bounds__(256) void clause_attn_kernel(
    const float* __restrict__ hs,         // [B, L, H]
    const float* __restrict__ fc_w,       // [H]
    const int*   __restrict__ clause_len, // [B, D]
    const int*   __restrict__ doc_len,    // [B]
    float*       __restrict__ out)        // [B, D, H]
{
    const int bd   = blockIdx.x;
    const int b    = bd >> 5;     // / Dc
    const int d    = bd & 31;     // % Dc
    const int tid  = threadIdx.x;
    const int lane = tid & 63;
    const int wave = tid >> 6;

    __shared__ float s_w[Hc];      // fc_w staged in LDS (3 KB)
    __shared__ float s_alpha[Cc];  // alphas, then softmax weights
    __shared__ int   s_n;
    __shared__ int   s_off;

    // Stage fc_w into LDS.
    for (int i = tid; i < Hc; i += 256) s_w[i] = fc_w[i];

    // Wave 0: lane-parallel exclusive prefix sum of clause_len[b, :].
    if (wave == 0) {
        int v = (lane < Dc) ? clause_len[b * Dc + lane] : 0;
        int sum = v;
        #pragma unroll
        for (int s = 1; s < 32; s <<= 1) {
            int o = __shfl_up(sum, s, 64);
            if (lane >= s) sum += o;
        }
        if (lane == d) {
            s_off = sum - v;                         // exclusive offset
            s_n   = (d < doc_len[b]) ? v : 0;        // valid-token count
        }
    }
    __syncthreads();

    const int n   = s_n;
    const int off = s_off;

    const float* hb = hs  + (size_t)b  * Lc * Hc;
    float*       ob = out + (size_t)bd * Hc;

    if (n == 0) {
        // All-masked clause: reference yields exactly 0 (uniform weights x zeroed sent).
        for (int i = tid; i < Hc; i += 256) ob[i] = 0.0f;
        return;
    }

    // Phase 1: alpha[c] = dot(hidden[row_c], fc_w). Wave w handles c = w, w+4, ...
    for (int c = wave; c < n; c += 4) {
        const int t = min(off + c, Lc - 1);
        const float* row = hb + (size_t)t * Hc;
        float acc = 0.0f;
        #pragma unroll
        for (int k = 0; k < Hc / 64; ++k)
            acc += row[lane + k * 64] * s_w[lane + k * 64];
        #pragma unroll
        for (int s = 32; s > 0; s >>= 1)
            acc += __shfl_down(acc, s, 64);
        if (lane == 0) s_alpha[c] = acc;
    }
    __syncthreads();

    // Phase 2: softmax over n values (wave 0). fc_b cancels; exp(NEG-max) == 0.0f.
    if (wave == 0) {
        float v = (lane < n) ? s_alpha[lane] : -INFINITY;
        float m = v;
        #pragma unroll
        for (int s = 32; s > 0; s >>= 1)
            m = fmaxf(m, __shfl_xor(m, s, 64));
        float e = (lane < n) ? __expf(v - m) : 0.0f;
        float sum = e;
        #pragma unroll
        for (int s = 32; s > 0; s >>= 1)
            sum += __shfl_xor(sum, s, 64);
        if (lane < n) s_alpha[lane] = e / sum;
    }
    __syncthreads();

    // Phase 3: out[h] = sum_c w[c] * hidden[row_c][h]; thread owns h = tid, tid+256, tid+512.
    float a0 = 0.0f, a1 = 0.0f, a2 = 0.0f;
    const float* row = hb + (size_t)min(off, Lc - 1) * Hc;
    for (int c = 0; c < n; ++c) {
        const float wc = s_alpha[c];
        a0 = fmaf(wc, row[tid],       a0);
        a1 = fmaf(wc, row[tid + 256], a1);
        a2 = fmaf(wc, row[tid + 512], a2);
        row += Hc;  // rows are contiguous; off+n-1 <= 2016 < Lc so clip never triggers mid-span
    }
    ob[tid]       = a0;
    ob[tid + 256] = a1;
    ob[tid + 512] = a2;
}

extern "C" void kernel_launch(void* const* d_in, const int* in_sizes, int n_in,
                              void* d_out, int out_size, void* d_ws, size_t ws_size,
                              hipStream_t stream) {
    const float* hs         = (const float*)d_in[0];  // [B, L, H]
    const float* fc_w       = (const float*)d_in[1];  // [H]
    // d_in[2] = fc_b — constant across softmax axis, cancels exactly; unused.
    const int*   clause_len = (const int*)d_in[3];    // [B, D]
    const int*   doc_len    = (const int*)d_in[4];    // [B]
    float*       out        = (float*)d_out;          // [B, D, H]

    clause_attn_kernel<<<Bc * Dc, 256, 0, stream>>>(hs, fc_w, clause_len, doc_len, out);
}

// Round 3
// 19.229 us; speedup vs baseline: 1.2622x; 1.2622x over previous
//
#include <hip/hip_runtime.h>
#include <hip/hip_bf16.h>

#define Bc 32
#define Lc 2048
#define Hc 768
#define Dc 32
#define Cc 64
#define WAVES 8
#define TPB (WAVES * 64)

// One block (512 threads = 8 waves) per (b, d) clause. Single pass over the
// clause's token rows with online-softmax (flash-style): each row is read from
// HBM exactly once; dot + softmax-weighted accumulation fused.
__global__ __launch_bounds__(TPB, 4) void clause_attn_fused(
    const float* __restrict__ hs,         // [B, L, H]
    const float* __restrict__ fc_w,       // [H]
    const int*   __restrict__ clause_len, // [B, D]
    const int*   __restrict__ doc_len,    // [B]
    float*       __restrict__ out)        // [B, D, H]
{
    const int bd   = blockIdx.x;
    const int b    = bd >> 5;     // / Dc
    const int d    = bd & 31;     // % Dc
    const int tid  = threadIdx.x;
    const int lane = tid & 63;
    const int wave = tid >> 6;

    __shared__ float s_m[WAVES];
    __shared__ float s_s[WAVES];
    __shared__ float s_acc[WAVES][Hc];   // 24 KB
    __shared__ int   s_n, s_off;

    // Wave 0: exclusive prefix sum of clause_len[b, :] (lanes 0..31).
    if (wave == 0) {
        int v = (lane < Dc) ? clause_len[b * Dc + lane] : 0;
        int sum = v;
        #pragma unroll
        for (int s = 1; s < 32; s <<= 1) {
            int o = __shfl_up(sum, s, 64);
            if (lane >= s) sum += o;
        }
        if (lane == d) {
            s_off = sum - v;                       // exclusive offset
            s_n   = (d < doc_len[b]) ? v : 0;      // valid-token count
        }
    }
    __syncthreads();

    const int n   = s_n;
    const int off = s_off;
    float* ob = out + (size_t)bd * Hc;

    if (n == 0) {
        // Fully-masked clause: reference = uniform weights x zeroed sent = 0.
        ob[tid] = 0.0f;
        if (tid < Hc - TPB) ob[TPB + tid] = 0.0f;
        return;
    }

    // fc_w in registers: lane owns h = chunk*256 + lane*4 + j.
    const int hbase = lane * 4;
    const float4 w0 = *(const float4*)(fc_w + hbase);
    const float4 w1 = *(const float4*)(fc_w + 256 + hbase);
    const float4 w2 = *(const float4*)(fc_w + 512 + hbase);

    const float* base = hs + (size_t)b * Lc * Hc;
    // off + n - 1 <= 1953 + 62 < Lc, so no clamping needed for valid slots.

    float m = -INFINITY, ssum = 0.0f;
    float4 a0 = {0,0,0,0}, a1 = {0,0,0,0}, a2 = {0,0,0,0};

    int c = wave;
    float4 v0, v1, v2;
    if (c < n) {
        const float* r = base + (size_t)(off + c) * Hc;
        v0 = *(const float4*)(r + hbase);
        v1 = *(const float4*)(r + 256 + hbase);
        v2 = *(const float4*)(r + 512 + hbase);
    }
    for (; c < n; c += WAVES) {
        // Prefetch next row for this wave (wave-uniform branch).
        float4 u0, u1, u2;
        const int cn = c + WAVES;
        if (cn < n) {
            const float* r = base + (size_t)(off + cn) * Hc;
            u0 = *(const float4*)(r + hbase);
            u1 = *(const float4*)(r + 256 + hbase);
            u2 = *(const float4*)(r + 512 + hbase);
        }
        // alpha = dot(row, fc_w) across the wave.
        float p = v0.x*w0.x + v0.y*w0.y + v0.z*w0.z + v0.w*w0.w
                + v1.x*w1.x + v1.y*w1.y + v1.z*w1.z + v1.w*w1.w
                + v2.x*w2.x + v2.y*w2.y + v2.z*w2.z + v2.w*w2.w;
        #pragma unroll
        for (int s = 32; s > 0; s >>= 1)
            p += __shfl_xor(p, s, 64);
        // Online-softmax update (all values wave-uniform except row data).
        const float M     = fmaxf(m, p);
        const float scale = __expf(m - M);   // first row: exp(-inf) = 0
        const float e     = __expf(p - M);
        ssum = ssum * scale + e;
        a0.x = a0.x*scale + e*v0.x;  a0.y = a0.y*scale + e*v0.y;
        a0.z = a0.z*scale + e*v0.z;  a0.w = a0.w*scale + e*v0.w;
        a1.x = a1.x*scale + e*v1.x;  a1.y = a1.y*scale + e*v1.y;
        a1.z = a1.z*scale + e*v1.z;  a1.w = a1.w*scale + e*v1.w;
        a2.x = a2.x*scale + e*v2.x;  a2.y = a2.y*scale + e*v2.y;
        a2.z = a2.z*scale + e*v2.z;  a2.w = a2.w*scale + e*v2.w;
        m = M;
        v0 = u0; v1 = u1; v2 = u2;
    }

    // Publish per-wave partial state.
    if (lane == 0) { s_m[wave] = m; s_s[wave] = ssum; }
    *(float4*)&s_acc[wave][hbase]       = a0;
    *(float4*)&s_acc[wave][256 + hbase] = a1;
    *(float4*)&s_acc[wave][512 + hbase] = a2;
    __syncthreads();

    // Merge 8 partials. n >= 1 so wave 0 contributed -> M finite, S > 0.
    float M = -INFINITY;
    #pragma unroll
    for (int w = 0; w < WAVES; ++w) M = fmaxf(M, s_m[w]);
    float f[WAVES];
    float S = 0.0f;
    #pragma unroll
    for (int w = 0; w < WAVES; ++w) {
        f[w] = __expf(s_m[w] - M);           // empty wave: exp(-inf) = 0
        S += f[w] * s_s[w];
    }
    const float rinv = 1.0f / S;

    float r0 = 0.0f;
    #pragma unroll
    for (int w = 0; w < WAVES; ++w) r0 += f[w] * s_acc[w][tid];
    ob[tid] = r0 * rinv;
    if (tid < Hc - TPB) {
        float r1 = 0.0f;
        #pragma unroll
        for (int w = 0; w < WAVES; ++w) r1 += f[w] * s_acc[w][TPB + tid];
        ob[TPB + tid] = r1 * rinv;
    }
}

extern "C" void kernel_launch(void* const* d_in, const int* in_sizes, int n_in,
                              void* d_out, int out_size, void* d_ws, size_t ws_size,
                              hipStream_t stream) {
    const float* hs         = (const float*)d_in[0];  // [B, L, H]
    const float* fc_w       = (const float*)d_in[1];  // [H]
    // d_in[2] = fc_b — constant across the softmax axis, cancels exactly.
    const int*   clause_len = (const int*)d_in[3];    // [B, D]
    const int*   doc_len    = (const int*)d_in[4];    // [B]
    float*       out        = (float*)d_out;          // [B, D, H]

    clause_attn_fused<<<Bc * Dc, TPB, 0, stream>>>(hs, fc_w, clause_len, doc_len, out);
}